// Round 3
// baseline (314.240 us; speedup 1.0000x reference)
//
#include <hip/hip_runtime.h>

// x (N,S,C,V) = (8,2048,4,64) fp32; embedding (C,K,V) = (4,512,64) fp32.
#define NROW 16384   // N*S
#define CCH  4
#define KCB  512
#define VDIM 64
#define ZW   8       // waves per block = K-chunks; each wave scans KCB/ZW = 64 codes

typedef __attribute__((ext_vector_type(16))) float sf16;

// Pre-kernel: e2[c*K+k] = sum_v emb[c][k][v]^2  (2048 floats into d_ws)
__global__ void e2_kernel(const float* __restrict__ emb, float* __restrict__ e2) {
    int i = blockIdx.x * blockDim.x + threadIdx.x;
    if (i >= CCH * KCB) return;
    const float* e = emb + (size_t)i * VDIM;
    float s = 0.f;
#pragma unroll
    for (int v = 0; v < VDIM; ++v) s = fmaf(e[v], e[v], s);
    e2[i] = s;
}

// Block = (64 rows, ZW K-chunks) = 512 threads, 8 waves; c = blockIdx.y.
// Inner loop: embedding forced into SGPRs via s_load_dwordx16 (wave-uniform
// address), x in 16-float chunks (L1-hot re-reads) -> bounded VGPR pressure,
// pure v_fmac_f32 with SGPR operand in the hot loop.
__global__ __launch_bounds__(512, 8)
void vq_kernel(const float* __restrict__ x, const float* __restrict__ emb,
               const float* __restrict__ e2w, float* __restrict__ out) {
    const int lane = threadIdx.x;                               // row within tile
    const int c = blockIdx.y;                                   // uniform channel
    const int z = __builtin_amdgcn_readfirstlane(threadIdx.y);  // wave-uniform K-chunk
    const int r = blockIdx.x * 64 + lane;

    const float4* xp = (const float4*)(x + ((size_t)r * CCH + c) * VDIM);

    // x2 = sum x^2 (transient registers; x stays L1-hot for the loop re-reads)
    float x2 = 0.f;
#pragma unroll
    for (int i = 0; i < 16; ++i) {
        const float4 t = xp[i];
        x2 = fmaf(t.x, t.x, x2); x2 = fmaf(t.y, t.y, x2);
        x2 = fmaf(t.z, t.z, x2); x2 = fmaf(t.w, t.w, x2);
    }

    const float* eb  = emb + (size_t)c * (KCB * VDIM);  // wave-uniform base
    const float* e2c = e2w + c * KCB;
    const int kbase = z * (KCB / ZW);

    float best = 3.4e38f;
    int bk = kbase;

    for (int kk = 0; kk < (KCB / ZW) / 4; ++kk) {       // 16 groups of 4 codes
        const int k0 = kbase + kk * 4;
        const float* e0 = eb + (size_t)k0 * VDIM;       // uniform
        float a0 = 0.f, a1 = 0.f, a2 = 0.f, a3 = 0.f;
#pragma unroll
        for (int vc = 0; vc < 4; ++vc) {
            // 4 codes' 16-float v-chunks -> 64 SGPRs, one self-contained block.
            // offsets: next code is 64 floats = 0x100 bytes away.
            sf16 q0, q1, q2, q3;
            asm volatile(
                "s_load_dwordx16 %0, %4, 0x0\n\t"
                "s_load_dwordx16 %1, %4, 0x100\n\t"
                "s_load_dwordx16 %2, %4, 0x200\n\t"
                "s_load_dwordx16 %3, %4, 0x300\n\t"
                "s_waitcnt lgkmcnt(0)"
                : "=s"(q0), "=s"(q1), "=s"(q2), "=s"(q3)
                : "s"(e0 + vc * 16));

            // x chunk (16 floats) from L1
            float xv[16];
#pragma unroll
            for (int i = 0; i < 4; ++i) {
                const float4 t = xp[vc * 4 + i];
                xv[4*i+0] = t.x; xv[4*i+1] = t.y; xv[4*i+2] = t.z; xv[4*i+3] = t.w;
            }
#pragma unroll
            for (int j = 0; j < 16; ++j) {
                a0 = fmaf(q0[j], xv[j], a0);
                a1 = fmaf(q1[j], xv[j], a1);
                a2 = fmaf(q2[j], xv[j], a2);
                a3 = fmaf(q3[j], xv[j], a3);
            }
        }
        // exact reference expression/order: (x2 - 2*xe) + e2
        const float d0 = (x2 - 2.0f * a0) + e2c[k0 + 0];
        const float d1 = (x2 - 2.0f * a1) + e2c[k0 + 1];
        const float d2 = (x2 - 2.0f * a2) + e2c[k0 + 2];
        const float d3 = (x2 - 2.0f * a3) + e2c[k0 + 3];
        if (d0 < best) { best = d0; bk = k0 + 0; }      // first-min tie-break
        if (d1 < best) { best = d1; bk = k0 + 1; }
        if (d2 < best) { best = d2; bk = k0 + 2; }
        if (d3 < best) { best = d3; bk = k0 + 3; }
    }

    // Combine ZW partial argmins (z ascending, strict < => global first-min)
    __shared__ float sd[ZW][64];
    __shared__ int   sk[ZW][64];
    sd[z][lane] = best;
    sk[z][lane] = bk;
    __syncthreads();

    if (z == 0) {
#pragma unroll
        for (int w = 1; w < ZW; ++w) {
            const float dw = sd[w][lane];
            const int   kw = sk[w][lane];
            if (dw < best) { best = dw; bk = kw; }
        }

        const float4* ep = (const float4*)(eb + (size_t)bk * VDIM);
        float4* o0 = (float4*)(out + ((size_t)r * CCH + c) * VDIM);
        float s = 0.f;
#pragma unroll
        for (int i = 0; i < 16; ++i) {
            const float4 e4 = ep[i];
            const float4 t = xp[i];           // L1-hot reload
            float4 w;
            // out0 = (output - x) + x, exactly as reference
            w.x = (e4.x - t.x) + t.x;
            w.y = (e4.y - t.y) + t.y;
            w.z = (e4.z - t.z) + t.z;
            w.w = (e4.w - t.w) + t.w;
            o0[i] = w;
            float dx;
            dx = t.x - e4.x; s = fmaf(dx, dx, s);
            dx = t.y - e4.y; s = fmaf(dx, dx, s);
            dx = t.z - e4.z; s = fmaf(dx, dx, s);
            dx = t.w - e4.w; s = fmaf(dx, dx, s);
        }
        const size_t base1 = (size_t)NROW * CCH * VDIM;
        const size_t base2 = base1 + (size_t)NROW * CCH;
        const size_t idx = (size_t)r * CCH + c;
        out[base1 + idx] = s;   // out1
        out[base2 + idx] = s;   // out2 (identical by construction)
    }
}

extern "C" void kernel_launch(void* const* d_in, const int* in_sizes, int n_in,
                              void* d_out, int out_size, void* d_ws, size_t ws_size,
                              hipStream_t stream) {
    const float* x   = (const float*)d_in[0];
    const float* emb = (const float*)d_in[1];
    float* out = (float*)d_out;
    float* e2w = (float*)d_ws;   // 8 KiB

    e2_kernel<<<dim3((CCH * KCB + 255) / 256), dim3(256), 0, stream>>>(emb, e2w);
    vq_kernel<<<dim3(NROW / 64, CCH), dim3(64, ZW), 0, stream>>>(x, emb, e2w, out);
}